// Round 1
// baseline (5798.798 us; speedup 1.0000x reference)
//
#include <hip/hip_runtime.h>
#include <math.h>

// Problem constants (b=1 hard-coded)
#define H  24
#define NN 3072
#define D  128
#define G  16
#define BM 192
#define TOPK_K 896
#define TQ 64
#define TK 64
#define PADR 68          // row stride (floats) for [d][row] LDS tiles: 68*4B=272 ≡ 0 mod 16
#define OUT2_OFF ((size_t)H * NN * D)

// RNG mode gamble: modern JAX (>=0.5) defaults jax_threefry_partitionable=True.
// If this round fails with absmax ~1e-2..5e-2, flip to 0 (legacy split/counter scheme).
#define PARTITIONABLE 1

__device__ __constant__ float SCALE = 0.08838834764831845f;  // 1/sqrt(128)

// ---------------- threefry2x32 (exact JAX semantics) ----------------
__device__ __forceinline__ void tf2x32(unsigned k0, unsigned k1, unsigned x0, unsigned x1,
                                       unsigned* o0, unsigned* o1) {
  unsigned ks2 = k0 ^ k1 ^ 0x1BD11BDAu;
  unsigned v0 = x0 + k0, v1 = x1 + k1;
#define TF_RND(r) { v0 += v1; v1 = (v1 << (r)) | (v1 >> (32 - (r))); v1 ^= v0; }
  TF_RND(13) TF_RND(15) TF_RND(26) TF_RND(6)   v0 += k1;  v1 += ks2 + 1u;
  TF_RND(17) TF_RND(29) TF_RND(16) TF_RND(24)  v0 += ks2; v1 += k0 + 2u;
  TF_RND(13) TF_RND(15) TF_RND(26) TF_RND(6)   v0 += k0;  v1 += k1 + 3u;
  TF_RND(17) TF_RND(29) TF_RND(16) TF_RND(24)  v0 += k1;  v1 += ks2 + 4u;
  TF_RND(13) TF_RND(15) TF_RND(26) TF_RND(6)   v0 += ks2; v1 += k0 + 5u;
#undef TF_RND
  *o0 = v0; *o1 = v1;
}

// mask[i] = 1.0f where randint(key(1), shape, 0, 100) == 0 else 0.0f
// root key data for jax.random.key(1) is (0, 1).
__global__ __launch_bounds__(256)
void rmask_kernel(float* __restrict__ mask) {
  const unsigned S = H * G * NN;  // 1179648
  unsigned i = blockIdx.x * 256u + threadIdx.x;
  if (i >= S) return;
  unsigned hb, lb, a, b;
#if PARTITIONABLE
  // fold-like split: child key j = full hash of 64-bit counter j (hi=0, lo=j)
  unsigned k1a, k1b, k2a, k2b;
  tf2x32(0u, 1u, 0u, 0u, &k1a, &k1b);
  tf2x32(0u, 1u, 0u, 1u, &k2a, &k2b);
  // partitionable random_bits (32-bit): bits[i] = H(key; 0, i).a ^ H(key; 0, i).b
  tf2x32(k1a, k1b, 0u, i, &a, &b); hb = a ^ b;
  tf2x32(k2a, k2b, 0u, i, &a, &b); lb = a ^ b;
#else
  // original split: counts = iota(4) paired (0,2),(1,3); k1 = firsts, k2 = seconds
  unsigned h0a, h0b, h1a, h1b;
  tf2x32(0u, 1u, 0u, 2u, &h0a, &h0b);
  tf2x32(0u, 1u, 1u, 3u, &h1a, &h1b);
  unsigned k1a = h0a, k1b = h1a, k2a = h0b, k2b = h1b;
  const unsigned HALF = S / 2u;
  if (i < HALF) {
    tf2x32(k1a, k1b, i, i + HALF, &a, &b); hb = a;
    tf2x32(k2a, k2b, i, i + HALF, &a, &b); lb = a;
  } else {
    tf2x32(k1a, k1b, i - HALF, i, &a, &b); hb = b;
    tf2x32(k2a, k2b, i - HALF, i, &a, &b); lb = b;
  }
#endif
  // randint: span=100, multiplier = ((2^16 % 100)^2) % 100 = 96
  unsigned r = ((hb % 100u) * 96u + (lb % 100u)) % 100u;
  mask[i] = (r == 0u) ? 1.0f : 0.0f;
}

// ---------------- row norms: qnorm[h*N+m], kmax[h] (as float bits, atomicMax) ----------------
__global__ __launch_bounds__(256)
void norms_kernel(const float* __restrict__ qg, const float* __restrict__ kg,
                  float* __restrict__ qnorm, unsigned int* __restrict__ kmaxb) {
  int gt = blockIdx.x * 256 + threadIdx.x;
  int wave = gt >> 6, lane = gt & 63;
  if (wave >= 2 * H * NN) return;
  const float* src = (wave < H * NN) ? qg : kg;
  int row = (wave < H * NN) ? wave : wave - H * NN;
  float2 x = ((const float2*)(src + (size_t)row * D))[lane];
  float s = x.x * x.x + x.y * x.y;
#pragma unroll
  for (int off = 32; off; off >>= 1) s += __shfl_xor(s, off);
  if (lane == 0) {
    float nrm = sqrtf(s);
    if (wave < H * NN) qnorm[row] = nrm;
    else atomicMax(kmaxb + (row / NN), __float_as_uint(nrm));
  }
}

// ---------------- shared helpers for the attention kernels ----------------
__device__ __forceinline__ void stage_k_half(const float* __restrict__ kh, int kc, int half,
                                             int tid, float kd_sh[TK][PADR]) {
#pragma unroll
  for (int it = 0; it < 4; ++it) {
    int f = tid + it * 256;             // 0..1023 : 64 cols x 16 float4
    int col = f >> 4, d4 = f & 15;
    float4 kv = ((const float4*)kh)[(size_t)(kc + col) * 32 + half * 16 + d4];
    int d = d4 * 4;
    kd_sh[d + 0][col] = kv.x;
    kd_sh[d + 1][col] = kv.y;
    kd_sh[d + 2][col] = kv.z;
    kd_sh[d + 3][col] = kv.w;
  }
}

__device__ __forceinline__ void dot_accum(const float q_sh[D][PADR], const float kd_sh[TK][PADR],
                                          int db, int ty, int tx, float s[4][4]) {
#pragma unroll 8
  for (int dd = 0; dd < 64; ++dd) {
    float4 qv = *(const float4*)&q_sh[db + dd][ty * 4];
    float4 kv = *(const float4*)&kd_sh[dd][tx * 4];
    s[0][0] = fmaf(qv.x, kv.x, s[0][0]); s[0][1] = fmaf(qv.x, kv.y, s[0][1]);
    s[0][2] = fmaf(qv.x, kv.z, s[0][2]); s[0][3] = fmaf(qv.x, kv.w, s[0][3]);
    s[1][0] = fmaf(qv.y, kv.x, s[1][0]); s[1][1] = fmaf(qv.y, kv.y, s[1][1]);
    s[1][2] = fmaf(qv.y, kv.z, s[1][2]); s[1][3] = fmaf(qv.y, kv.w, s[1][3]);
    s[2][0] = fmaf(qv.z, kv.x, s[2][0]); s[2][1] = fmaf(qv.z, kv.y, s[2][1]);
    s[2][2] = fmaf(qv.z, kv.z, s[2][2]); s[2][3] = fmaf(qv.z, kv.w, s[2][3]);
    s[3][0] = fmaf(qv.w, kv.x, s[3][0]); s[3][1] = fmaf(qv.w, kv.y, s[3][1]);
    s[3][2] = fmaf(qv.w, kv.z, s[3][2]); s[3][3] = fmaf(qv.w, kv.w, s[3][3]);
  }
}

__device__ __forceinline__ void pv_accum(const float* __restrict__ p_sh,
                                         const float* __restrict__ vh, int kc,
                                         int ty, int tx, float oacc[4][8]) {
#pragma unroll 2
  for (int kk = 0; kk < TK; kk += 4) {
    float er[4][4];
#pragma unroll
    for (int j = 0; j < 4; ++j) {
      float4 t = *(const float4*)&p_sh[(ty * 4 + j) * PADR + kk];
      er[j][0] = t.x; er[j][1] = t.y; er[j][2] = t.z; er[j][3] = t.w;
    }
#pragma unroll
    for (int u = 0; u < 4; ++u) {
      const float* vrow = vh + (size_t)(kc + kk + u) * D + tx * 8;
      float4 v0 = *(const float4*)(vrow);
      float4 v1 = *(const float4*)(vrow + 4);
#pragma unroll
      for (int j = 0; j < 4; ++j) {
        float e = er[j][u];
        oacc[j][0] = fmaf(e, v0.x, oacc[j][0]);
        oacc[j][1] = fmaf(e, v0.y, oacc[j][1]);
        oacc[j][2] = fmaf(e, v0.z, oacc[j][2]);
        oacc[j][3] = fmaf(e, v0.w, oacc[j][3]);
        oacc[j][4] = fmaf(e, v1.x, oacc[j][4]);
        oacc[j][5] = fmaf(e, v1.y, oacc[j][5]);
        oacc[j][6] = fmaf(e, v1.z, oacc[j][6]);
        oacc[j][7] = fmaf(e, v1.w, oacc[j][7]);
      }
    }
  }
}

// ---------------- dense attention: o (first half of out) + CS (atomicAdd) ----------------
__global__ __launch_bounds__(256)
void dense_kernel(const float* __restrict__ qg, const float* __restrict__ kg,
                  const float* __restrict__ vg, const float* __restrict__ qnorm,
                  const unsigned int* __restrict__ kmaxb,
                  float* __restrict__ out, float* __restrict__ csb) {
  __shared__ float q_sh[D][PADR];    // [d][row] 34.8 KB
  __shared__ float kd_sh[TK][PADR];  // [d_half][col] 17.4 KB; also p-tile / reduction scratch
  __shared__ float invL_sh[TQ];

  const int tid = threadIdx.x;
  const int tx = tid & 15, ty = tid >> 4;
  const int h = blockIdx.y;
  const int m0 = blockIdx.x * TQ;
  const float* qh = qg + ((size_t)h * NN + m0) * D;
  const float* kh = kg + (size_t)h * NN * D;
  const float* vh = vg + (size_t)h * NN * D;

  // stage q transposed [d][row] (once per block)
#pragma unroll
  for (int it = 0; it < 8; ++it) {
    int f = tid + it * 256;           // 0..2047 : 64 rows x 32 float4
    int row = f >> 5, d4 = f & 31;
    float4 qv = ((const float4*)qh)[row * 32 + d4];
    int d = d4 * 4;
    q_sh[d + 0][row] = qv.x; q_sh[d + 1][row] = qv.y;
    q_sh[d + 2][row] = qv.z; q_sh[d + 3][row] = qv.w;
  }
  float kmax = __uint_as_float(kmaxb[h]);
  float Mr[4];
#pragma unroll
  for (int j = 0; j < 4; ++j)
    Mr[j] = SCALE * qnorm[(size_t)h * NN + m0 + ty * 4 + j] * kmax;
  __syncthreads();

  // ---- pass A: row denominators L (stabilizer = norm bound, never overflows) ----
  float Lacc[4] = {0.f, 0.f, 0.f, 0.f};
  for (int kc = 0; kc < NN; kc += TK) {
    float s[4][4] = {};
#pragma unroll
    for (int half = 0; half < 2; ++half) {
      __syncthreads();
      stage_k_half(kh, kc, half, tid, kd_sh);
      __syncthreads();
      dot_accum(q_sh, kd_sh, half * 64, ty, tx, s);
    }
#pragma unroll
    for (int j = 0; j < 4; ++j)
#pragma unroll
      for (int jj = 0; jj < 4; ++jj)
        Lacc[j] += expf(fmaf(s[j][jj], SCALE, -Mr[j]));
  }
  __syncthreads();
  {
    float* red = &kd_sh[0][0];  // [TQ][17]
#pragma unroll
    for (int j = 0; j < 4; ++j) red[(ty * 4 + j) * 17 + tx] = Lacc[j];
    __syncthreads();
    if (tid < TQ) {
      float L = 0.f;
#pragma unroll
      for (int t = 0; t < 16; ++t) L += red[tid * 17 + t];
      invL_sh[tid] = 1.0f / L;
    }
  }
  __syncthreads();
  float invLr[4];
#pragma unroll
  for (int j = 0; j < 4; ++j) invLr[j] = invL_sh[ty * 4 + j];

  // ---- pass B: p = e/L, accumulate o and CS ----
  float oacc[4][8] = {};
  const int g = m0 / BM;
  for (int kc = 0; kc < NN; kc += TK) {
    float s[4][4] = {};
#pragma unroll
    for (int half = 0; half < 2; ++half) {
      __syncthreads();
      stage_k_half(kh, kc, half, tid, kd_sh);
      __syncthreads();
      dot_accum(q_sh, kd_sh, half * 64, ty, tx, s);
    }
    __syncthreads();                      // k-tile consumed; reuse LDS as p-tile
    float* p_sh = &kd_sh[0][0];           // [row][PADR]
#pragma unroll
    for (int j = 0; j < 4; ++j)
#pragma unroll
      for (int jj = 0; jj < 4; ++jj)
        p_sh[(ty * 4 + j) * PADR + tx * 4 + jj] =
            expf(fmaf(s[j][jj], SCALE, -Mr[j])) * invLr[j];
    __syncthreads();
    // column sums of p -> CS (3 blocks per query group accumulate via atomics)
    if (tid < TK) {
      float csum = 0.f;
      for (int m = 0; m < TQ; ++m) csum += p_sh[m * PADR + tid];
      atomicAdd(&csb[((size_t)h * G + g) * NN + kc + tid], csum);
    }
    pv_accum(p_sh, vh, kc, ty, tx, oacc);
    __syncthreads();                      // before next chunk overwrites p-tile
  }
  // write o
#pragma unroll
  for (int j = 0; j < 4; ++j) {
    float* orow = out + ((size_t)h * NN + m0 + ty * 4 + j) * D + tx * 8;
    *(float4*)(orow)     = make_float4(oacc[j][0], oacc[j][1], oacc[j][2], oacc[j][3]);
    *(float4*)(orow + 4) = make_float4(oacc[j][4], oacc[j][5], oacc[j][6], oacc[j][7]);
  }
}

// ---------------- exact top-k selection per (h,g): mask |= top-896 of cs ----------------
__global__ __launch_bounds__(256)
void topk_kernel(const float* __restrict__ csb, float* __restrict__ maskb) {
  const int hg = blockIdx.x;
  const float* cs = csb + (size_t)hg * NN;
  float* mask = maskb + (size_t)hg * NN;
  __shared__ unsigned int vals[NN];  // 12 KB; cs > 0 so uint order == float order
  __shared__ int wsum[4];
  const int tid = threadIdx.x;
  for (int i = tid; i < NN; i += 256) vals[i] = __float_as_uint(cs[i]);
  __syncthreads();
  // greedy MSB search: largest T with count(v >= T) >= K  ->  T = K-th largest value
  unsigned int T = 0u;
  for (int b = 31; b >= 0; --b) {
    unsigned int cand = T | (1u << b);
    int c = 0;
    for (int i = tid; i < NN; i += 256) c += (vals[i] >= cand) ? 1 : 0;
#pragma unroll
    for (int off = 32; off; off >>= 1) c += __shfl_xor(c, off);
    if ((tid & 63) == 0) wsum[tid >> 6] = c;
    __syncthreads();
    int total = wsum[0] + wsum[1] + wsum[2] + wsum[3];
    if (total >= TOPK_K) T = cand;
    __syncthreads();
  }
  // lax.top_k tie-break: all (> T), then (== T) in increasing index order
  int c = 0;
  for (int i = tid; i < NN; i += 256) c += (vals[i] > T) ? 1 : 0;
#pragma unroll
  for (int off = 32; off; off >>= 1) c += __shfl_xor(c, off);
  if ((tid & 63) == 0) wsum[tid >> 6] = c;
  __syncthreads();
  int cgt = wsum[0] + wsum[1] + wsum[2] + wsum[3];
  int need = TOPK_K - cgt;
  for (int i = tid; i < NN; i += 256)
    if (vals[i] > T) mask[i] = 1.0f;
  __syncthreads();
  if (tid == 0) {
    int c2 = 0;
    for (int i = 0; i < NN && c2 < need; ++i)
      if (vals[i] == T) { mask[i] = 1.0f; ++c2; }
  }
}

// ---------------- sparse attention (single pass) -> out2 = o - sp ----------------
__global__ __launch_bounds__(256)
void sparse_kernel(const float* __restrict__ qg, const float* __restrict__ kg,
                   const float* __restrict__ vg, const float* __restrict__ qnorm,
                   const unsigned int* __restrict__ kmaxb,
                   const float* __restrict__ maskb, float* __restrict__ out) {
  __shared__ float q_sh[D][PADR];
  __shared__ float kd_sh[TK][PADR];
  __shared__ float invL_sh[TQ];

  const int tid = threadIdx.x;
  const int tx = tid & 15, ty = tid >> 4;
  const int h = blockIdx.y;
  const int m0 = blockIdx.x * TQ;
  const float* qh = qg + ((size_t)h * NN + m0) * D;
  const float* kh = kg + (size_t)h * NN * D;
  const float* vh = vg + (size_t)h * NN * D;
  const int g = m0 / BM;
  const float* mrow = maskb + ((size_t)h * G + g) * NN;

#pragma unroll
  for (int it = 0; it < 8; ++it) {
    int f = tid + it * 256;
    int row = f >> 5, d4 = f & 31;
    float4 qv = ((const float4*)qh)[row * 32 + d4];
    int d = d4 * 4;
    q_sh[d + 0][row] = qv.x; q_sh[d + 1][row] = qv.y;
    q_sh[d + 2][row] = qv.z; q_sh[d + 3][row] = qv.w;
  }
  float kmax = __uint_as_float(kmaxb[h]);
  float Mr[4];
#pragma unroll
  for (int j = 0; j < 4; ++j)
    Mr[j] = SCALE * qnorm[(size_t)h * NN + m0 + ty * 4 + j] * kmax;
  __syncthreads();

  float lacc[4] = {0.f, 0.f, 0.f, 0.f};
  float oacc[4][8] = {};
  for (int kc = 0; kc < NN; kc += TK) {
    float s[4][4] = {};
#pragma unroll
    for (int half = 0; half < 2; ++half) {
      __syncthreads();
      stage_k_half(kh, kc, half, tid, kd_sh);
      __syncthreads();
      dot_accum(q_sh, kd_sh, half * 64, ty, tx, s);
    }
    float4 mv = *(const float4*)&mrow[kc + tx * 4];
    float mj[4] = {mv.x, mv.y, mv.z, mv.w};
    __syncthreads();
    float* p_sh = &kd_sh[0][0];
#pragma unroll
    for (int j = 0; j < 4; ++j)
#pragma unroll
      for (int jj = 0; jj < 4; ++jj) {
        float e = expf(fmaf(s[j][jj], SCALE, -Mr[j])) * mj[jj];
        p_sh[(ty * 4 + j) * PADR + tx * 4 + jj] = e;
        lacc[j] += e;
      }
    __syncthreads();
    pv_accum(p_sh, vh, kc, ty, tx, oacc);
    __syncthreads();
  }
  // reduce masked denominators across tx
  {
    float* red = &kd_sh[0][0];
#pragma unroll
    for (int j = 0; j < 4; ++j) red[(ty * 4 + j) * 17 + tx] = lacc[j];
    __syncthreads();
    if (tid < TQ) {
      float l = 0.f;
#pragma unroll
      for (int t = 0; t < 16; ++t) l += red[tid * 17 + t];
      invL_sh[tid] = 1.0f / l;
    }
  }
  __syncthreads();
  // out2 = o - oacc/l
#pragma unroll
  for (int j = 0; j < 4; ++j) {
    float il = invL_sh[ty * 4 + j];
    const float* orow = out + ((size_t)h * NN + m0 + ty * 4 + j) * D + tx * 8;
    float4 o0 = *(const float4*)(orow);
    float4 o1 = *(const float4*)(orow + 4);
    float4 r0 = make_float4(o0.x - oacc[j][0] * il, o0.y - oacc[j][1] * il,
                            o0.z - oacc[j][2] * il, o0.w - oacc[j][3] * il);
    float4 r1 = make_float4(o1.x - oacc[j][4] * il, o1.y - oacc[j][5] * il,
                            o1.z - oacc[j][6] * il, o1.w - oacc[j][7] * il);
    float* drow = out + OUT2_OFF + ((size_t)h * NN + m0 + ty * 4 + j) * D + tx * 8;
    *(float4*)(drow)     = r0;
    *(float4*)(drow + 4) = r1;
  }
}

// ---------------- launch ----------------
extern "C" void kernel_launch(void* const* d_in, const int* in_sizes, int n_in,
                              void* d_out, int out_size, void* d_ws, size_t ws_size,
                              hipStream_t stream) {
  const float* q = (const float*)d_in[0];
  const float* k = (const float*)d_in[1];
  const float* v = (const float*)d_in[2];
  float* out = (float*)d_out;
  float* ws = (float*)d_ws;

  // ws layout (floats): qnorm[H*NN] | kmax[32 (24 used, padded)] | CS[H*G*NN] | MASK[H*G*NN]
  float* qnorm = ws;
  unsigned int* kmaxb = (unsigned int*)(ws + H * NN);
  float* csb = ws + H * NN + 32;
  float* maskb = csb + (size_t)H * G * NN;
  // total ~9.7 MB

  // zero qnorm/kmax/CS (CS is atomically accumulated; MASK is fully overwritten)
  hipMemsetAsync(d_ws, 0, (size_t)(H * NN + 32 + (size_t)H * G * NN) * sizeof(float), stream);

  norms_kernel<<<dim3(2 * H * NN / 4), dim3(256), 0, stream>>>(q, k, qnorm, kmaxb);
  rmask_kernel<<<dim3(H * G * NN / 256), dim3(256), 0, stream>>>(maskb);
  dense_kernel<<<dim3(NN / TQ, H), dim3(256), 0, stream>>>(q, k, v, qnorm, kmaxb, out, csb);
  topk_kernel<<<dim3(H * G), dim3(256), 0, stream>>>(csb, maskb);
  sparse_kernel<<<dim3(NN / TQ, H), dim3(256), 0, stream>>>(q, k, v, qnorm, kmaxb, maskb, out);
}

// Round 5
// 3243.266 us; speedup vs baseline: 1.7880x; 1.7880x over previous
//
#include <hip/hip_runtime.h>
#include <math.h>

// Problem constants (b=1 hard-coded)
#define H  24
#define NN 3072
#define D  128
#define G  16
#define BM 192
#define TOPK_K 896
#define TQb 128            // query rows per block (4 waves x 32 rows)
#define TKb 64             // keys per k-tile
#define PST 68             // P-tile LDS row stride (floats)
#define OUT2_OFF ((size_t)H * NN * D)
#define KV_HALF_BYTES ((size_t)H * NN * D * 2)   // 18874368
#define CSD_BYTES ((size_t)H * G * NN * 8)       // 9437184 (float64 cs)

// exp(s*scale) = exp2(s * scale * log2(e)); scale = 1/sqrt(128)
#define LOG2E_SCALE 0.12751743822f

typedef _Float16 half8 __attribute__((ext_vector_type(8)));
typedef _Float16 half4v __attribute__((ext_vector_type(4)));
typedef __fp16 fp16x2 __attribute__((ext_vector_type(2)));
typedef float floatx4 __attribute__((ext_vector_type(4)));

__device__ __forceinline__ floatx4 fzero4() {
  floatx4 z = {0.f, 0.f, 0.f, 0.f};
  return z;
}
// RTE pack (unbiased) — used for input fragments
__device__ __forceinline__ half8 pack_h8_rte(float4 a, float4 b) {
  half8 r;
  r[0] = (_Float16)a.x; r[1] = (_Float16)a.y; r[2] = (_Float16)a.z; r[3] = (_Float16)a.w;
  r[4] = (_Float16)b.x; r[5] = (_Float16)b.y; r[6] = (_Float16)b.z; r[7] = (_Float16)b.w;
  return r;
}
// RTZ packed cvt (1 instr per pair) — used for P (p>=0; small bias cancels in o - sp)
__device__ __forceinline__ half8 pack_h8_rtz(float4 a, float4 b) {
  fp16x2 h0 = __builtin_amdgcn_cvt_pkrtz(a.x, a.y);
  fp16x2 h1 = __builtin_amdgcn_cvt_pkrtz(a.z, a.w);
  fp16x2 h2 = __builtin_amdgcn_cvt_pkrtz(b.x, b.y);
  fp16x2 h3 = __builtin_amdgcn_cvt_pkrtz(b.z, b.w);
  half8 r;
  r[0] = (_Float16)h0[0]; r[1] = (_Float16)h0[1];
  r[2] = (_Float16)h1[0]; r[3] = (_Float16)h1[1];
  r[4] = (_Float16)h2[0]; r[5] = (_Float16)h2[1];
  r[6] = (_Float16)h3[0]; r[7] = (_Float16)h3[1];
  return r;
}
// residual: x - (float)f16(x)
__device__ __forceinline__ half8 pack_h8_residual(float4 a, float4 b, half8 hi) {
  float4 ra = make_float4(a.x - (float)hi[0], a.y - (float)hi[1],
                          a.z - (float)hi[2], a.w - (float)hi[3]);
  float4 rb = make_float4(b.x - (float)hi[4], b.y - (float)hi[5],
                          b.z - (float)hi[6], b.w - (float)hi[7]);
  return pack_h8_rte(ra, rb);
}

// ---------------- threefry2x32 (exact JAX semantics, validated round 1) ----------------
__device__ __forceinline__ void tf2x32(unsigned k0, unsigned k1, unsigned x0, unsigned x1,
                                       unsigned* o0, unsigned* o1) {
  unsigned ks2 = k0 ^ k1 ^ 0x1BD11BDAu;
  unsigned v0 = x0 + k0, v1 = x1 + k1;
#define TF_RND(r) { v0 += v1; v1 = (v1 << (r)) | (v1 >> (32 - (r))); v1 ^= v0; }
  TF_RND(13) TF_RND(15) TF_RND(26) TF_RND(6)   v0 += k1;  v1 += ks2 + 1u;
  TF_RND(17) TF_RND(29) TF_RND(16) TF_RND(24)  v0 += ks2; v1 += k0 + 2u;
  TF_RND(13) TF_RND(15) TF_RND(26) TF_RND(6)   v0 += k0;  v1 += k1 + 3u;
  TF_RND(17) TF_RND(29) TF_RND(16) TF_RND(24)  v0 += k1;  v1 += ks2 + 4u;
  TF_RND(13) TF_RND(15) TF_RND(26) TF_RND(6)   v0 += ks2; v1 += k0 + 5u;
#undef TF_RND
  *o0 = v0; *o1 = v1;
}

__global__ __launch_bounds__(256)
void rmask_kernel(float* __restrict__ mask) {
  const unsigned S = H * G * NN;
  unsigned i = blockIdx.x * 256u + threadIdx.x;
  if (i >= S) return;
  unsigned hb, lb, a, b;
  unsigned k1a, k1b, k2a, k2b;
  tf2x32(0u, 1u, 0u, 0u, &k1a, &k1b);
  tf2x32(0u, 1u, 0u, 1u, &k2a, &k2b);
  tf2x32(k1a, k1b, 0u, i, &a, &b); hb = a ^ b;
  tf2x32(k2a, k2b, 0u, i, &a, &b); lb = a ^ b;
  unsigned r = ((hb % 100u) * 96u + (lb % 100u)) % 100u;
  mask[i] = (r == 0u) ? 1.0f : 0.0f;
}

// ---------------- phase 0: k -> f16 hi + f16 residual (row-major) ----------------
__global__ __launch_bounds__(256)
void cvt_k_kernel(const float* __restrict__ k, _Float16* __restrict__ khi,
                  _Float16* __restrict__ klo) {
  size_t i = (size_t)blockIdx.x * 256 + threadIdx.x;   // 8 elems per thread
  const float4* src = (const float4*)k + i * 2;
  float4 a = src[0], b = src[1];
  half8 hi = pack_h8_rte(a, b);
  *(half8*)(khi + i * 8) = hi;
  *(half8*)(klo + i * 8) = pack_h8_residual(a, b, hi);
}

// ---------------- phase 0: v -> f16 transposed vT[h][d][key] ----------------
__global__ __launch_bounds__(256)
void cvt_vT_kernel(const float* __restrict__ v, _Float16* __restrict__ vT) {
  __shared__ _Float16 t[64][68];
  const int h = blockIdx.z, k0 = blockIdx.x * 64, d0 = blockIdx.y * 64;
  const int tid = threadIdx.x;
  const int c4 = tid & 15, r = tid >> 4;
#pragma unroll
  for (int i = 0; i < 4; ++i) {
    int row = r + i * 16;  // key row within tile
    float4 x = *(const float4*)(v + ((size_t)(h * NN + k0 + row)) * D + d0 + c4 * 4);
    t[c4 * 4 + 0][row] = (_Float16)x.x;
    t[c4 * 4 + 1][row] = (_Float16)x.y;
    t[c4 * 4 + 2][row] = (_Float16)x.z;
    t[c4 * 4 + 3][row] = (_Float16)x.w;
  }
  __syncthreads();
#pragma unroll
  for (int i = 0; i < 4; ++i) {
    int drow = r + i * 16;  // d within tile
    half4v val = *(const half4v*)&t[drow][c4 * 4];
    *(half4v*)(vT + (size_t)(h * D + d0 + drow) * NN + k0 + c4 * 4) = val;
  }
}

// ---------------- dense attention: fused 2-pass MFMA (split-f16 QK^T), o + f64 cs ----------------
__global__ __launch_bounds__(256, 2)
void dense_kernel(const float* __restrict__ q, const _Float16* __restrict__ khi_g,
                  const _Float16* __restrict__ klo_g, const _Float16* __restrict__ vT,
                  float* __restrict__ out, double* __restrict__ csb) {
  __shared__ float p_sh[TQb * PST];   // per-wave private 32-row stripes; NO barriers needed
  const int tid = threadIdx.x;
  const int wave = tid >> 6, lane = tid & 63;
  const int l15 = lane & 15, l4 = lane >> 4;
  const int h = blockIdx.y;
  const int m0 = blockIdx.x * TQb;
  const int rowbase = m0 + wave * 32;
  const _Float16* khi = khi_g + (size_t)h * NN * D;
  const _Float16* klo = klo_g + (size_t)h * NN * D;
  const _Float16* vh = vT + (size_t)h * D * NN;
  float* p_wave = p_sh + wave * 32 * PST;

  // Q A-fragments hi+lo, register-resident: A[m=l15][k=l4*8+j]
  half8 qh[2][4], ql[2][4];
#pragma unroll
  for (int mt = 0; mt < 2; ++mt)
#pragma unroll
    for (int ds = 0; ds < 4; ++ds) {
      const float* qp = q + ((size_t)(h * NN + rowbase + mt * 16 + l15)) * D + ds * 32 + l4 * 8;
      float4 a = *(const float4*)qp, b = *(const float4*)(qp + 4);
      qh[mt][ds] = pack_h8_rte(a, b);
      ql[mt][ds] = pack_h8_residual(a, b, qh[mt][ds]);
    }

  // ---- pass 1: per-lane partial row sums (split-precision QK^T) ----
  float Lacc[2][4] = {{0.f, 0.f, 0.f, 0.f}, {0.f, 0.f, 0.f, 0.f}};
  for (int kc = 0; kc < NN; kc += TKb) {
    floatx4 S[2][4];
#pragma unroll
    for (int mt = 0; mt < 2; ++mt)
#pragma unroll
      for (int nt = 0; nt < 4; ++nt) S[mt][nt] = fzero4();
#pragma unroll
    for (int nt = 0; nt < 4; ++nt) {
      const size_t koff = (size_t)(kc + nt * 16 + l15) * D + l4 * 8;
#pragma unroll
      for (int ds = 0; ds < 4; ++ds) {
        half8 kbh = *(const half8*)(khi + koff + ds * 32);
        half8 kbl = *(const half8*)(klo + koff + ds * 32);
        S[0][nt] = __builtin_amdgcn_mfma_f32_16x16x32_f16(qh[0][ds], kbh, S[0][nt], 0, 0, 0);
        S[1][nt] = __builtin_amdgcn_mfma_f32_16x16x32_f16(qh[1][ds], kbh, S[1][nt], 0, 0, 0);
        S[0][nt] = __builtin_amdgcn_mfma_f32_16x16x32_f16(qh[0][ds], kbl, S[0][nt], 0, 0, 0);
        S[1][nt] = __builtin_amdgcn_mfma_f32_16x16x32_f16(qh[1][ds], kbl, S[1][nt], 0, 0, 0);
        S[0][nt] = __builtin_amdgcn_mfma_f32_16x16x32_f16(ql[0][ds], kbh, S[0][nt], 0, 0, 0);
        S[1][nt] = __builtin_amdgcn_mfma_f32_16x16x32_f16(ql[1][ds], kbh, S[1][nt], 0, 0, 0);
      }
    }
#pragma unroll
    for (int mt = 0; mt < 2; ++mt)
#pragma unroll
      for (int nt = 0; nt < 4; ++nt)
#pragma unroll
        for (int r = 0; r < 4; ++r)
          Lacc[mt][r] += __builtin_amdgcn_exp2f(S[mt][nt][r] * LOG2E_SCALE);
  }
  float invL[2][4];
  double dinvL[2][4];
#pragma unroll
  for (int mt = 0; mt < 2; ++mt)
#pragma unroll
    for (int r = 0; r < 4; ++r) {
      float x = Lacc[mt][r];
      x += __shfl_xor(x, 1); x += __shfl_xor(x, 2);
      x += __shfl_xor(x, 4); x += __shfl_xor(x, 8);
      invL[mt][r] = 1.0f / x;   // row = mt*16 + l4*4 + r  (matches C-layout)
      dinvL[mt][r] = (double)invL[mt][r];
    }

  // ---- pass 2: p, cs (f64 atomics), PV ----
  const int gg0 = rowbase / BM;
  floatx4 O[2][8];
#pragma unroll
  for (int mt = 0; mt < 2; ++mt)
#pragma unroll
    for (int dt = 0; dt < 8; ++dt) O[mt][dt] = fzero4();

  for (int kc = 0; kc < NN; kc += TKb) {
    floatx4 S[2][4];
#pragma unroll
    for (int mt = 0; mt < 2; ++mt)
#pragma unroll
      for (int nt = 0; nt < 4; ++nt) S[mt][nt] = fzero4();
#pragma unroll
    for (int nt = 0; nt < 4; ++nt) {
      const size_t koff = (size_t)(kc + nt * 16 + l15) * D + l4 * 8;
#pragma unroll
      for (int ds = 0; ds < 4; ++ds) {
        half8 kbh = *(const half8*)(khi + koff + ds * 32);
        half8 kbl = *(const half8*)(klo + koff + ds * 32);
        S[0][nt] = __builtin_amdgcn_mfma_f32_16x16x32_f16(qh[0][ds], kbh, S[0][nt], 0, 0, 0);
        S[1][nt] = __builtin_amdgcn_mfma_f32_16x16x32_f16(qh[1][ds], kbh, S[1][nt], 0, 0, 0);
        S[0][nt] = __builtin_amdgcn_mfma_f32_16x16x32_f16(qh[0][ds], kbl, S[0][nt], 0, 0, 0);
        S[1][nt] = __builtin_amdgcn_mfma_f32_16x16x32_f16(qh[1][ds], kbl, S[1][nt], 0, 0, 0);
        S[0][nt] = __builtin_amdgcn_mfma_f32_16x16x32_f16(ql[0][ds], kbh, S[0][nt], 0, 0, 0);
        S[1][nt] = __builtin_amdgcn_mfma_f32_16x16x32_f16(ql[1][ds], kbh, S[1][nt], 0, 0, 0);
      }
    }
#pragma unroll
    for (int mt = 0; mt < 2; ++mt) {
#pragma unroll
      for (int nt = 0; nt < 4; ++nt) {
        float e0 = __builtin_amdgcn_exp2f(S[mt][nt][0] * LOG2E_SCALE);
        float e1 = __builtin_amdgcn_exp2f(S[mt][nt][1] * LOG2E_SCALE);
        float e2 = __builtin_amdgcn_exp2f(S[mt][nt][2] * LOG2E_SCALE);
        float e3 = __builtin_amdgcn_exp2f(S[mt][nt][3] * LOG2E_SCALE);
        // cs partial in float64: kills accumulation-order noise (the top-k flip driver)
        double csp = (double)e0 * dinvL[mt][0] + (double)e1 * dinvL[mt][1]
                   + (double)e2 * dinvL[mt][2] + (double)e3 * dinvL[mt][3];
        int base = (mt * 16 + l4 * 4) * PST + nt * 16 + l15;
        p_wave[base] = e0; p_wave[base + PST] = e1;
        p_wave[base + 2 * PST] = e2; p_wave[base + 3 * PST] = e3;
        atomicAdd(&csb[((size_t)h * G + gg0) * NN + kc + nt * 16 + l15], csp);
      }
    }
    // PV: A = P (LDS round-trip), B = vT direct 16B loads
#pragma unroll
    for (int ks = 0; ks < 2; ++ks) {
      half8 pa[2];
#pragma unroll
      for (int mt = 0; mt < 2; ++mt) {
        const float* pp = p_wave + (mt * 16 + l15) * PST + ks * 32 + l4 * 8;
        pa[mt] = pack_h8_rtz(*(const float4*)pp, *(const float4*)(pp + 4));
      }
#pragma unroll
      for (int dt = 0; dt < 8; ++dt) {
        half8 vb = *(const half8*)(vh + (size_t)(dt * 16 + l15) * NN + kc + ks * 32 + l4 * 8);
        O[0][dt] = __builtin_amdgcn_mfma_f32_16x16x32_f16(pa[0], vb, O[0][dt], 0, 0, 0);
        O[1][dt] = __builtin_amdgcn_mfma_f32_16x16x32_f16(pa[1], vb, O[1][dt], 0, 0, 0);
      }
    }
  }
  // epilogue: normalize rows, store o
#pragma unroll
  for (int mt = 0; mt < 2; ++mt)
#pragma unroll
    for (int dt = 0; dt < 8; ++dt)
#pragma unroll
      for (int r = 0; r < 4; ++r) {
        size_t idx = ((size_t)h * NN + rowbase + mt * 16 + l4 * 4 + r) * D + dt * 16 + l15;
        out[idx] = O[mt][dt][r] * invL[mt][r];
      }
}

// ---------------- exact top-k per (h,g) on f64 cs: mask |= top-896 ----------------
__global__ __launch_bounds__(256)
void topk_kernel(const double* __restrict__ csb, float* __restrict__ maskb) {
  const int hg = blockIdx.x;
  const double* cs = csb + (size_t)hg * NN;
  float* mask = maskb + (size_t)hg * NN;
  __shared__ unsigned long long vals[NN];  // 24 KB; cs > 0 so u64 order == double order
  __shared__ int wsum[4];
  const int tid = threadIdx.x;
  for (int i = tid; i < NN; i += 256)
    vals[i] = (unsigned long long)__double_as_longlong(cs[i]);
  __syncthreads();
  // greedy MSB search: largest T with count(v >= T) >= K  ->  T = K-th largest value
  unsigned long long T = 0ull;
  for (int b = 62; b >= 0; --b) {
    unsigned long long cand = T | (1ull << b);
    int c = 0;
    for (int i = tid; i < NN; i += 256) c += (vals[i] >= cand) ? 1 : 0;
#pragma unroll
    for (int off = 32; off; off >>= 1) c += __shfl_xor(c, off);
    if ((tid & 63) == 0) wsum[tid >> 6] = c;
    __syncthreads();
    int total = wsum[0] + wsum[1] + wsum[2] + wsum[3];
    if (total >= TOPK_K) T = cand;
    __syncthreads();
  }
  // lax.top_k tie-break: all (> T), then (== T) in increasing index order
  int c = 0;
  for (int i = tid; i < NN; i += 256) c += (vals[i] > T) ? 1 : 0;
#pragma unroll
  for (int off = 32; off; off >>= 1) c += __shfl_xor(c, off);
  if ((tid & 63) == 0) wsum[tid >> 6] = c;
  __syncthreads();
  int cgt = wsum[0] + wsum[1] + wsum[2] + wsum[3];
  int need = TOPK_K - cgt;
  for (int i = tid; i < NN; i += 256)
    if (vals[i] > T) mask[i] = 1.0f;
  __syncthreads();
  if (tid == 0) {
    int c2 = 0;
    for (int i = 0; i < NN && c2 < need; ++i)
      if (vals[i] == T) { mask[i] = 1.0f; ++c2; }
  }
}

// ---------------- sparse attention (single pass, plain f16) -> out2 = o - sp ----------------
__global__ __launch_bounds__(256, 2)
void sparse_kernel(const float* __restrict__ q, const _Float16* __restrict__ kf,
                   const _Float16* __restrict__ vT, const float* __restrict__ maskb,
                   float* __restrict__ out) {
  __shared__ float p_sh[TQb * PST];
  const int tid = threadIdx.x;
  const int wave = tid >> 6, lane = tid & 63;
  const int l15 = lane & 15, l4 = lane >> 4;
  const int h = blockIdx.y;
  const int m0 = blockIdx.x * TQb;
  const int rowbase = m0 + wave * 32;
  const _Float16* kh = kf + (size_t)h * NN * D;
  const _Float16* vh = vT + (size_t)h * D * NN;
  float* p_wave = p_sh + wave * 32 * PST;

  half8 qa[2][4];
#pragma unroll
  for (int mt = 0; mt < 2; ++mt)
#pragma unroll
    for (int ds = 0; ds < 4; ++ds) {
      const float* qp = q + ((size_t)(h * NN + rowbase + mt * 16 + l15)) * D + ds * 32 + l4 * 8;
      qa[mt][ds] = pack_h8_rte(*(const float4*)qp, *(const float4*)(qp + 4));
    }

  const int gg0 = rowbase / BM;
  const float* mrow = maskb + ((size_t)h * G + gg0) * NN;

  float lacc[2][4] = {{0.f, 0.f, 0.f, 0.f}, {0.f, 0.f, 0.f, 0.f}};
  floatx4 O[2][8];
#pragma unroll
  for (int mt = 0; mt < 2; ++mt)
#pragma unroll
    for (int dt = 0; dt < 8; ++dt) O[mt][dt] = fzero4();

  for (int kc = 0; kc < NN; kc += TKb) {
    floatx4 S[2][4];
#pragma unroll
    for (int mt = 0; mt < 2; ++mt)
#pragma unroll
      for (int nt = 0; nt < 4; ++nt) S[mt][nt] = fzero4();
#pragma unroll
    for (int nt = 0; nt < 4; ++nt) {
      const _Float16* kp = kh + (size_t)(kc + nt * 16 + l15) * D + l4 * 8;
#pragma unroll
      for (int ds = 0; ds < 4; ++ds) {
        half8 kb = *(const half8*)(kp + ds * 32);
        S[0][nt] = __builtin_amdgcn_mfma_f32_16x16x32_f16(qa[0][ds], kb, S[0][nt], 0, 0, 0);
        S[1][nt] = __builtin_amdgcn_mfma_f32_16x16x32_f16(qa[1][ds], kb, S[1][nt], 0, 0, 0);
      }
    }
#pragma unroll
    for (int mt = 0; mt < 2; ++mt) {
#pragma unroll
      for (int nt = 0; nt < 4; ++nt) {
        float mv = mrow[kc + nt * 16 + l15];
        float e0 = __builtin_amdgcn_exp2f(S[mt][nt][0] * LOG2E_SCALE) * mv;
        float e1 = __builtin_amdgcn_exp2f(S[mt][nt][1] * LOG2E_SCALE) * mv;
        float e2 = __builtin_amdgcn_exp2f(S[mt][nt][2] * LOG2E_SCALE) * mv;
        float e3 = __builtin_amdgcn_exp2f(S[mt][nt][3] * LOG2E_SCALE) * mv;
        lacc[mt][0] += e0; lacc[mt][1] += e1; lacc[mt][2] += e2; lacc[mt][3] += e3;
        int base = (mt * 16 + l4 * 4) * PST + nt * 16 + l15;
        p_wave[base] = e0; p_wave[base + PST] = e1;
        p_wave[base + 2 * PST] = e2; p_wave[base + 3 * PST] = e3;
      }
    }
#pragma unroll
    for (int ks = 0; ks < 2; ++ks) {
      half8 pa[2];
#pragma unroll
      for (int mt = 0; mt < 2; ++mt) {
        const float* pp = p_wave + (mt * 16 + l15) * PST + ks * 32 + l4 * 8;
        pa[mt] = pack_h8_rtz(*(const float4*)pp, *(const float4*)(pp + 4));
      }
#pragma unroll
      for (int dt = 0; dt < 8; ++dt) {
        half8 vb = *(const half8*)(vh + (size_t)(dt * 16 + l15) * NN + kc + ks * 32 + l4 * 8);
        O[0][dt] = __builtin_amdgcn_mfma_f32_16x16x32_f16(pa[0], vb, O[0][dt], 0, 0, 0);
        O[1][dt] = __builtin_amdgcn_mfma_f32_16x16x32_f16(pa[1], vb, O[1][dt], 0, 0, 0);
      }
    }
  }
  float invl[2][4];
#pragma unroll
  for (int mt = 0; mt < 2; ++mt)
#pragma unroll
    for (int r = 0; r < 4; ++r) {
      float x = lacc[mt][r];
      x += __shfl_xor(x, 1); x += __shfl_xor(x, 2);
      x += __shfl_xor(x, 4); x += __shfl_xor(x, 8);
      invl[mt][r] = 1.0f / x;
    }
#pragma unroll
  for (int mt = 0; mt < 2; ++mt)
#pragma unroll
    for (int dt = 0; dt < 8; ++dt)
#pragma unroll
      for (int r = 0; r < 4; ++r) {
        size_t idx = ((size_t)h * NN + rowbase + mt * 16 + l4 * 4 + r) * D + dt * 16 + l15;
        out[OUT2_OFF + idx] = out[idx] - O[mt][dt][r] * invl[mt][r];
      }
}

// ---------------- launch ----------------
extern "C" void kernel_launch(void* const* d_in, const int* in_sizes, int n_in,
                              void* d_out, int out_size, void* d_ws, size_t ws_size,
                              hipStream_t stream) {
  const float* q = (const float*)d_in[0];
  const float* k = (const float*)d_in[1];
  const float* v = (const float*)d_in[2];
  float* out = (float*)d_out;
  char* wsb = (char*)d_ws;

  // ws layout: khi | klo | vT | cs(double) | mask   (~71 MB total)
  _Float16* khi = (_Float16*)wsb;
  _Float16* klo = (_Float16*)(wsb + KV_HALF_BYTES);
  _Float16* vT  = (_Float16*)(wsb + 2 * KV_HALF_BYTES);
  double* csb   = (double*)(wsb + 3 * KV_HALF_BYTES);
  float* maskb  = (float*)(wsb + 3 * KV_HALF_BYTES + CSD_BYTES);

  (void)hipMemsetAsync(csb, 0, CSD_BYTES, stream);
  cvt_k_kernel<<<dim3((H * NN * D) / (8 * 256)), dim3(256), 0, stream>>>(k, khi, klo);
  cvt_vT_kernel<<<dim3(NN / 64, D / 64, H), dim3(256), 0, stream>>>(v, vT);
  rmask_kernel<<<dim3(H * G * NN / 256), dim3(256), 0, stream>>>(maskb);
  dense_kernel<<<dim3(NN / TQb, H), dim3(256), 0, stream>>>(q, khi, klo, vT, out, csb);
  topk_kernel<<<dim3(H * G), dim3(256), 0, stream>>>(csb, maskb);
  sparse_kernel<<<dim3(NN / TQb, H), dim3(256), 0, stream>>>(q, khi, vT, maskb, out);
}